// Round 1
// baseline (253.072 us; speedup 1.0000x reference)
//
#include <hip/hip_runtime.h>
#include <cstdint>

// GCN 2-layer forward on MI355X.
// Layer 1: h = relu((A_hat x) W1 + b1)   -- aggregate at 64ch, then GEMM 64->128
// Layer 2: out = A_hat (h W2) + b2       -- GEMM 128->64, then aggregate at 64ch
// A_hat applied via CSR-by-dst built once per launch (atomics + single-block scan).

#define IN_C 64
#define HID_C 128
#define OUT_C 64

// ---------------- edge dtype handling (int64 vs int32, decided on device) ----
__global__ void detect_i64(const unsigned int* __restrict__ ei, int* __restrict__ flag) {
    if (blockIdx.x == 0 && threadIdx.x == 0) {
        int is64 = 1;
#pragma unroll
        for (int i = 0; i < 16; ++i) is64 &= (ei[2 * i + 1] == 0u) ? 1 : 0;
        *flag = is64;  // values < 50000 -> int64 layout has all-zero high dwords
    }
}

__device__ __forceinline__ int edge_val(const void* ei, long long idx, int is64) {
    if (is64) return (int)((const long long*)ei)[idx];
    return ((const int*)ei)[idx];
}

// ---------------- degree histogram -------------------------------------------
__global__ void count_deg(const void* __restrict__ ei, int E, const int* __restrict__ flag,
                          int* __restrict__ indeg) {
    int e = blockIdx.x * blockDim.x + threadIdx.x;
    int is64 = *flag;
    if (e < E) {
        int d = edge_val(ei, (long long)E + e, is64);
        atomicAdd(&indeg[d], 1);
    }
}

__global__ void dinv_k(const int* __restrict__ indeg, float* __restrict__ dinv, int N) {
    int n = blockIdx.x * blockDim.x + threadIdx.x;
    if (n < N) dinv[n] = rsqrtf((float)(indeg[n] + 1));  // +1 self loop, deg>=1 always
}

// ---------------- single-block exclusive scan (rowptr) -----------------------
__global__ __launch_bounds__(1024) void scan_k(const int* __restrict__ indeg,
                                               int* __restrict__ rowptr, int n) {
    __shared__ int wsum[16];
    __shared__ int woff[16];
    __shared__ int chunk_total;
    __shared__ int carry_s;
    const int tid = threadIdx.x;
    const int lane = tid & 63;
    const int wid = tid >> 6;
    if (tid == 0) carry_s = 0;
    __syncthreads();
    for (int base = 0; base < n; base += 1024) {
        int i = base + tid;
        int v = (i < n) ? indeg[i] : 0;
        int s = v;
#pragma unroll
        for (int off = 1; off < 64; off <<= 1) {
            int t = __shfl_up(s, off, 64);
            if (lane >= off) s += t;
        }
        if (lane == 63) wsum[wid] = s;
        __syncthreads();
        if (wid == 0) {
            int ws = (lane < 16) ? wsum[lane] : 0;
            int t = ws;
#pragma unroll
            for (int off = 1; off < 16; off <<= 1) {
                int u = __shfl_up(t, off, 64);
                if (lane >= off) t += u;
            }
            if (lane < 16) woff[lane] = t - ws;
            if (lane == 15) chunk_total = t;
        }
        __syncthreads();
        if (i < n) rowptr[i] = carry_s + woff[wid] + (s - v);  // exclusive
        __syncthreads();
        if (tid == 0) carry_s += chunk_total;
        __syncthreads();
    }
    if (tid == 0) rowptr[n] = carry_s;
}

// ---------------- CSR fill: packed (src, norm) per entry ---------------------
__global__ void fill_csr(const void* __restrict__ ei, int E, const int* __restrict__ flag,
                         const int* __restrict__ rowptr, int* __restrict__ fillc,
                         const float* __restrict__ dinv, int2* __restrict__ edata) {
    int e = blockIdx.x * blockDim.x + threadIdx.x;
    if (e >= E) return;
    int is64 = *flag;
    int s = edge_val(ei, e, is64);
    int d = edge_val(ei, (long long)E + e, is64);
    int pos = rowptr[d] + atomicAdd(&fillc[d], 1);
    float wt = dinv[s] * dinv[d];
    edata[pos] = make_int2(s, __float_as_int(wt));
}

// ---------------- aggregation: one wave per node, lane = channel (64ch) ------
template <bool BIAS>
__global__ __launch_bounds__(256) void aggregate64_k(const float* __restrict__ feat,
                                                     const int* __restrict__ rowptr,
                                                     const int2* __restrict__ edata,
                                                     const float* __restrict__ dinv,
                                                     const float* __restrict__ bias,
                                                     float* __restrict__ out, int N) {
    int node = blockIdx.x * 4 + (threadIdx.x >> 6);
    int lane = threadIdx.x & 63;
    if (node >= N) return;
    float dn = dinv[node];
    float acc = feat[(size_t)node * 64 + lane] * (dn * dn);  // self loop
    int e = rowptr[node];
    int e1 = rowptr[node + 1];
    for (; e + 3 < e1; e += 4) {  // 4 gathers in flight
        int2 d0 = edata[e], d1 = edata[e + 1], d2 = edata[e + 2], d3 = edata[e + 3];
        float f0 = feat[(size_t)d0.x * 64 + lane];
        float f1 = feat[(size_t)d1.x * 64 + lane];
        float f2 = feat[(size_t)d2.x * 64 + lane];
        float f3 = feat[(size_t)d3.x * 64 + lane];
        acc = fmaf(__int_as_float(d0.y), f0, acc);
        acc = fmaf(__int_as_float(d1.y), f1, acc);
        acc = fmaf(__int_as_float(d2.y), f2, acc);
        acc = fmaf(__int_as_float(d3.y), f3, acc);
    }
    for (; e < e1; ++e) {
        int2 d = edata[e];
        acc = fmaf(__int_as_float(d.y), feat[(size_t)d.x * 64 + lane], acc);
    }
    if (BIAS) acc += bias[lane];
    out[(size_t)node * 64 + lane] = acc;
}

// ---------------- f32 GEMM: C[M,N] = A[M,K] @ B[K,N], optional bias+relu -----
// BM=64 rows/block, 256 threads, thread tile TM=8 x TN=N/32. Full K in LDS.
template <int K, int N, bool RELU>
__global__ __launch_bounds__(256) void gemm_k(const float* __restrict__ A,
                                              const float* __restrict__ B,
                                              const float* __restrict__ bias,
                                              float* __restrict__ C, int M) {
    constexpr int BM = 64;
    constexpr int TM = 8;
    constexpr int TN = N / 32;
    __shared__ float As[BM * K];
    __shared__ float Bs[K * N];
    const int tid = threadIdx.x;
    const int row0 = blockIdx.x * BM;

    {
        const float4* B4 = (const float4*)B;
        float4* Bs4 = (float4*)Bs;
        for (int i = tid; i < K * N / 4; i += 256) Bs4[i] = B4[i];
        float4* As4 = (float4*)As;
        for (int i = tid; i < BM * K / 4; i += 256) {
            int idx = i * 4;
            int r = idx / K;
            int gr = row0 + r;
            float4 v = make_float4(0.f, 0.f, 0.f, 0.f);
            if (gr < M) v = *(const float4*)(A + (size_t)gr * K + (idx & (K - 1)));
            As4[i] = v;
        }
    }
    __syncthreads();

    const int rg = tid >> 5;  // 0..7
    const int cg = tid & 31;  // 0..31
    float acc[TM][TN];
#pragma unroll
    for (int i = 0; i < TM; ++i)
#pragma unroll
        for (int j = 0; j < TN; ++j) acc[i][j] = 0.f;

#pragma unroll 4
    for (int k = 0; k < K; ++k) {
        float a[TM], b[TN];
#pragma unroll
        for (int i = 0; i < TM; ++i) a[i] = As[(rg * TM + i) * K + k];
#pragma unroll
        for (int j = 0; j < TN; ++j) b[j] = Bs[k * N + cg * TN + j];
#pragma unroll
        for (int i = 0; i < TM; ++i)
#pragma unroll
            for (int j = 0; j < TN; ++j) acc[i][j] = fmaf(a[i], b[j], acc[i][j]);
    }

    float bb[TN];
    if (RELU) {
#pragma unroll
        for (int j = 0; j < TN; ++j) bb[j] = bias[cg * TN + j];
    }
#pragma unroll
    for (int i = 0; i < TM; ++i) {
        int r = row0 + rg * TM + i;
        if (r < M) {
#pragma unroll
            for (int j = 0; j < TN; ++j) {
                float v = acc[i][j];
                if (RELU) v = fmaxf(v + bb[j], 0.f);
                C[(size_t)r * N + cg * TN + j] = v;
            }
        }
    }
}

// ---------------- launch -----------------------------------------------------
extern "C" void kernel_launch(void* const* d_in, const int* in_sizes, int n_in,
                              void* d_out, int out_size, void* d_ws, size_t ws_size,
                              hipStream_t stream) {
    (void)n_in; (void)out_size; (void)ws_size;
    const float* x  = (const float*)d_in[0];
    const void*  ei = d_in[1];
    const float* W1 = (const float*)d_in[2];
    const float* b1 = (const float*)d_in[3];
    const float* W2 = (const float*)d_in[4];
    const float* b2 = (const float*)d_in[5];
    float* out = (float*)d_out;
    const int N = in_sizes[0] / IN_C;   // 50000
    const int E = in_sizes[1] / 2;      // 800000

    char* p = (char*)d_ws;
    auto take = [&](size_t bytes) {
        char* r = p;
        p += (bytes + 255) & ~(size_t)255;
        return r;
    };
    int*   indeg  = (int*)take((size_t)N * 4);
    int*   fillc  = (int*)take((size_t)N * 4);
    int*   flag   = (int*)take(256);
    int*   rowptr = (int*)take(((size_t)N + 1) * 4);
    float* dinv   = (float*)take((size_t)N * 4);
    int2*  edata  = (int2*)take((size_t)E * 8);
    float* agg1   = (float*)take((size_t)N * IN_C * 4);
    float* h      = (float*)take((size_t)N * HID_C * 4);
    float* hw2    = (float*)take((size_t)N * OUT_C * 4);

    // zero indeg + fillc (contiguous at ws start)
    hipMemsetAsync(d_ws, 0, (size_t)((char*)(fillc + N) - (char*)d_ws), stream);

    detect_i64<<<1, 64, 0, stream>>>((const unsigned int*)ei, flag);
    count_deg<<<(E + 255) / 256, 256, 0, stream>>>(ei, E, flag, indeg);
    dinv_k<<<(N + 255) / 256, 256, 0, stream>>>(indeg, dinv, N);
    scan_k<<<1, 1024, 0, stream>>>(indeg, rowptr, N);
    fill_csr<<<(E + 255) / 256, 256, 0, stream>>>(ei, E, flag, rowptr, fillc, dinv, edata);

    // layer 1: agg1 = A_hat x ; h = relu(agg1 @ W1 + b1)
    aggregate64_k<false><<<(N + 3) / 4, 256, 0, stream>>>(x, rowptr, edata, dinv, nullptr, agg1, N);
    gemm_k<IN_C, HID_C, true><<<(N + 63) / 64, 256, 0, stream>>>(agg1, W1, b1, h, N);

    // layer 2: hw2 = h @ W2 ; out = A_hat hw2 + b2
    gemm_k<HID_C, OUT_C, false><<<(N + 63) / 64, 256, 0, stream>>>(h, W2, nullptr, hw2, N);
    aggregate64_k<true><<<(N + 3) / 4, 256, 0, stream>>>(hw2, rowptr, edata, dinv, b2, out, N);
}

// Round 2
// 213.465 us; speedup vs baseline: 1.1855x; 1.1855x over previous
//
#include <hip/hip_runtime.h>
#include <cstdint>

// GCN 2-layer forward on MI355X.
// Layer 1: h = relu((A_hat x) W1 + b1)   -- aggregate at 64ch, then GEMM 64->128
// Layer 2: out = A_hat (h W2) + b2       -- GEMM 128->64, then aggregate at 64ch
// CSR-by-dst built per launch: histogram -> 3-kernel hierarchical scan -> cursor fill.

#define IN_C 64
#define HID_C 128
#define OUT_C 64

// ---------------- edge dtype handling (int64 vs int32, decided on device) ----
__global__ void detect_i64(const unsigned int* __restrict__ ei, int* __restrict__ flag) {
    if (blockIdx.x == 0 && threadIdx.x == 0) {
        int is64 = 1;
#pragma unroll
        for (int i = 0; i < 16; ++i) is64 &= (ei[2 * i + 1] == 0u) ? 1 : 0;
        *flag = is64;  // values < 50000 -> int64 layout has all-zero high dwords
    }
}

__device__ __forceinline__ int edge_val(const void* ei, long long idx, int is64) {
    if (is64) return (int)((const long long*)ei)[idx];
    return ((const int*)ei)[idx];
}

// ---------------- degree histogram -------------------------------------------
__global__ void count_deg(const void* __restrict__ ei, int E, const int* __restrict__ flag,
                          int* __restrict__ indeg) {
    int e = blockIdx.x * blockDim.x + threadIdx.x;
    int is64 = *flag;
    if (e < E) {
        int d = edge_val(ei, (long long)E + e, is64);
        atomicAdd(&indeg[d], 1);
    }
}

// ---------------- hierarchical exclusive scan (3 kernels) --------------------
// partial: per-256-elem block scan; also emits dinv = rsqrt(deg+1)
__global__ __launch_bounds__(256) void partial_scan_k(const int* __restrict__ indeg,
                                                      int* __restrict__ rowptr,
                                                      float* __restrict__ dinv,
                                                      int* __restrict__ bsum, int n) {
    __shared__ int wsum[4];
    const int tid = threadIdx.x;
    const int i = blockIdx.x * 256 + tid;
    const int lane = tid & 63;
    const int wid = tid >> 6;
    int v = (i < n) ? indeg[i] : 0;
    if (i < n) dinv[i] = rsqrtf((float)(v + 1));  // +1 self loop
    int s = v;
#pragma unroll
    for (int off = 1; off < 64; off <<= 1) {
        int t = __shfl_up(s, off, 64);
        if (lane >= off) s += t;
    }
    if (lane == 63) wsum[wid] = s;
    __syncthreads();
    int woff = 0;
#pragma unroll
    for (int j = 0; j < 4; ++j)
        if (j < wid) woff += wsum[j];
    if (i < n) rowptr[i] = woff + s - v;  // block-local exclusive
    if (tid == 255) bsum[blockIdx.x] = woff + s;
}

__global__ __launch_bounds__(256) void scan_sums_k(const int* __restrict__ bsum,
                                                   int* __restrict__ boff, int nb) {
    __shared__ int wsum[4];
    const int tid = threadIdx.x;
    const int lane = tid & 63;
    const int wid = tid >> 6;
    int v = (tid < nb) ? bsum[tid] : 0;
    int s = v;
#pragma unroll
    for (int off = 1; off < 64; off <<= 1) {
        int t = __shfl_up(s, off, 64);
        if (lane >= off) s += t;
    }
    if (lane == 63) wsum[wid] = s;
    __syncthreads();
    int woff = 0;
#pragma unroll
    for (int j = 0; j < 4; ++j)
        if (j < wid) woff += wsum[j];
    boff[tid] = woff + s - v;  // exclusive
}

// finalize rowptr, and write cursor copy for the atomic fill
__global__ __launch_bounds__(256) void add_off_k(int* __restrict__ rowptr,
                                                 int* __restrict__ cursor,
                                                 const int* __restrict__ boff,
                                                 int n, int total) {
    int i = blockIdx.x * 256 + threadIdx.x;
    if (i < n) {
        int v = rowptr[i] + boff[blockIdx.x];
        rowptr[i] = v;
        cursor[i] = v;
    }
    if (i == 0) rowptr[n] = total;
}

// ---------------- CSR fill: packed (src, norm) per entry ---------------------
__global__ void fill_csr(const void* __restrict__ ei, int E, const int* __restrict__ flag,
                         int* __restrict__ cursor, const float* __restrict__ dinv,
                         int2* __restrict__ edata) {
    int e = blockIdx.x * blockDim.x + threadIdx.x;
    if (e >= E) return;
    int is64 = *flag;
    int s = edge_val(ei, e, is64);
    int d = edge_val(ei, (long long)E + e, is64);
    int pos = atomicAdd(&cursor[d], 1);
    float wt = dinv[s] * dinv[d];
    edata[pos] = make_int2(s, __float_as_int(wt));
}

// ---------------- aggregation: one wave per node, lane = channel (64ch) ------
template <bool BIAS>
__global__ __launch_bounds__(256) void aggregate64_k(const float* __restrict__ feat,
                                                     const int* __restrict__ rowptr,
                                                     const int2* __restrict__ edata,
                                                     const float* __restrict__ dinv,
                                                     const float* __restrict__ bias,
                                                     float* __restrict__ out, int N) {
    int node = blockIdx.x * 4 + (threadIdx.x >> 6);
    int lane = threadIdx.x & 63;
    if (node >= N) return;
    float dn = dinv[node];
    float acc = feat[(size_t)node * 64 + lane] * (dn * dn);  // self loop
    int e = rowptr[node];
    int e1 = rowptr[node + 1];
    for (; e + 3 < e1; e += 4) {  // 4 gathers in flight
        int2 d0 = edata[e], d1 = edata[e + 1], d2 = edata[e + 2], d3 = edata[e + 3];
        float f0 = feat[(size_t)d0.x * 64 + lane];
        float f1 = feat[(size_t)d1.x * 64 + lane];
        float f2 = feat[(size_t)d2.x * 64 + lane];
        float f3 = feat[(size_t)d3.x * 64 + lane];
        acc = fmaf(__int_as_float(d0.y), f0, acc);
        acc = fmaf(__int_as_float(d1.y), f1, acc);
        acc = fmaf(__int_as_float(d2.y), f2, acc);
        acc = fmaf(__int_as_float(d3.y), f3, acc);
    }
    for (; e < e1; ++e) {
        int2 d = edata[e];
        acc = fmaf(__int_as_float(d.y), feat[(size_t)d.x * 64 + lane], acc);
    }
    if (BIAS) acc += bias[lane];
    out[(size_t)node * 64 + lane] = acc;
}

// ---------------- f32 GEMM: C[M,N] = A[M,K] @ B[K,N], optional bias+relu -----
template <int K, int N, bool RELU>
__global__ __launch_bounds__(256) void gemm_k(const float* __restrict__ A,
                                              const float* __restrict__ B,
                                              const float* __restrict__ bias,
                                              float* __restrict__ C, int M) {
    constexpr int BM = 64;
    constexpr int TM = 8;
    constexpr int TN = N / 32;
    __shared__ float As[BM * K];
    __shared__ float Bs[K * N];
    const int tid = threadIdx.x;
    const int row0 = blockIdx.x * BM;

    {
        const float4* B4 = (const float4*)B;
        float4* Bs4 = (float4*)Bs;
        for (int i = tid; i < K * N / 4; i += 256) Bs4[i] = B4[i];
        float4* As4 = (float4*)As;
        for (int i = tid; i < BM * K / 4; i += 256) {
            int idx = i * 4;
            int r = idx / K;
            int gr = row0 + r;
            float4 v = make_float4(0.f, 0.f, 0.f, 0.f);
            if (gr < M) v = *(const float4*)(A + (size_t)gr * K + (idx & (K - 1)));
            As4[i] = v;
        }
    }
    __syncthreads();

    const int rg = tid >> 5;  // 0..7
    const int cg = tid & 31;  // 0..31
    float acc[TM][TN];
#pragma unroll
    for (int i = 0; i < TM; ++i)
#pragma unroll
        for (int j = 0; j < TN; ++j) acc[i][j] = 0.f;

#pragma unroll 4
    for (int k = 0; k < K; ++k) {
        float a[TM], b[TN];
#pragma unroll
        for (int i = 0; i < TM; ++i) a[i] = As[(rg * TM + i) * K + k];
#pragma unroll
        for (int j = 0; j < TN; ++j) b[j] = Bs[k * N + cg * TN + j];
#pragma unroll
        for (int i = 0; i < TM; ++i)
#pragma unroll
            for (int j = 0; j < TN; ++j) acc[i][j] = fmaf(a[i], b[j], acc[i][j]);
    }

    float bb[TN];
    if (RELU) {
#pragma unroll
        for (int j = 0; j < TN; ++j) bb[j] = bias[cg * TN + j];
    }
#pragma unroll
    for (int i = 0; i < TM; ++i) {
        int r = row0 + rg * TM + i;
        if (r < M) {
#pragma unroll
            for (int j = 0; j < TN; ++j) {
                float v = acc[i][j];
                if (RELU) v = fmaxf(v + bb[j], 0.f);
                C[(size_t)r * N + cg * TN + j] = v;
            }
        }
    }
}

// ---------------- launch -----------------------------------------------------
extern "C" void kernel_launch(void* const* d_in, const int* in_sizes, int n_in,
                              void* d_out, int out_size, void* d_ws, size_t ws_size,
                              hipStream_t stream) {
    (void)n_in; (void)out_size; (void)ws_size;
    const float* x  = (const float*)d_in[0];
    const void*  ei = d_in[1];
    const float* W1 = (const float*)d_in[2];
    const float* b1 = (const float*)d_in[3];
    const float* W2 = (const float*)d_in[4];
    const float* b2 = (const float*)d_in[5];
    float* out = (float*)d_out;
    const int N = in_sizes[0] / IN_C;   // 50000
    const int E = in_sizes[1] / 2;      // 800000
    const int NB = (N + 255) / 256;     // scan blocks (196)

    char* p = (char*)d_ws;
    auto take = [&](size_t bytes) {
        char* r = p;
        p += (bytes + 255) & ~(size_t)255;
        return r;
    };
    int*   indeg  = (int*)take((size_t)N * 4);   // memset region start
    int*   flag   = (int*)take(256);
    int*   rowptr = (int*)take(((size_t)N + 1) * 4);
    int*   cursor = (int*)take((size_t)N * 4);
    float* dinv   = (float*)take((size_t)N * 4);
    int*   bsum   = (int*)take(1024);
    int*   boff   = (int*)take(1024);
    int2*  edata  = (int2*)take((size_t)E * 8);
    float* agg1   = (float*)take((size_t)N * IN_C * 4);
    float* h      = (float*)take((size_t)N * HID_C * 4);
    float* hw2    = (float*)take((size_t)N * OUT_C * 4);

    hipMemsetAsync(indeg, 0, (size_t)N * 4, stream);

    detect_i64<<<1, 64, 0, stream>>>((const unsigned int*)ei, flag);
    count_deg<<<(E + 255) / 256, 256, 0, stream>>>(ei, E, flag, indeg);
    partial_scan_k<<<NB, 256, 0, stream>>>(indeg, rowptr, dinv, bsum, N);
    scan_sums_k<<<1, 256, 0, stream>>>(bsum, boff, NB);
    add_off_k<<<NB, 256, 0, stream>>>(rowptr, cursor, boff, N, E);
    fill_csr<<<(E + 255) / 256, 256, 0, stream>>>(ei, E, flag, cursor, dinv, edata);

    // layer 1: agg1 = A_hat x ; h = relu(agg1 @ W1 + b1)
    aggregate64_k<false><<<(N + 3) / 4, 256, 0, stream>>>(x, rowptr, edata, dinv, nullptr, agg1, N);
    gemm_k<IN_C, HID_C, true><<<(N + 63) / 64, 256, 0, stream>>>(agg1, W1, b1, h, N);

    // layer 2: hw2 = h @ W2 ; out = A_hat hw2 + b2
    gemm_k<HID_C, OUT_C, false><<<(N + 63) / 64, 256, 0, stream>>>(h, W2, nullptr, hw2, N);
    aggregate64_k<true><<<(N + 3) / 4, 256, 0, stream>>>(hw2, rowptr, edata, dinv, b2, out, N);
}

// Round 3
// 201.777 us; speedup vs baseline: 1.2542x; 1.0579x over previous
//
#include <hip/hip_runtime.h>
#include <cstdint>

// GCN 2-layer forward on MI355X.
// Layer 1: h = relu((A_hat x) W1 + b1)   -- aggregate at 64ch, then GEMM 64->128
// Layer 2: out = A_hat (h W2) + b2       -- GEMM 128->64, then aggregate at 64ch
// CSR-by-dst built per launch: histogram -> hierarchical scan -> 2-pass bucketed
// fill (partition by dst>>8 with LDS staging, then per-bucket LDS-cursor scatter)
// to avoid the 8x HBM write amplification of random 8B stores.

#define IN_C 64
#define HID_C 128
#define OUT_C 64
#define CH 4096  // edges per partition block

// ---------------- edge dtype handling (int64 vs int32, decided on device) ----
__global__ void detect_i64(const unsigned int* __restrict__ ei, int* __restrict__ flag) {
    if (blockIdx.x == 0 && threadIdx.x == 0) {
        int is64 = 1;
#pragma unroll
        for (int i = 0; i < 16; ++i) is64 &= (ei[2 * i + 1] == 0u) ? 1 : 0;
        *flag = is64;  // values < 50000 -> int64 layout has all-zero high dwords
    }
}

__device__ __forceinline__ int edge_val(const void* ei, long long idx, int is64) {
    if (is64) return (int)((const long long*)ei)[idx];
    return ((const int*)ei)[idx];
}

// ---------------- degree histogram -------------------------------------------
__global__ void count_deg(const void* __restrict__ ei, int E, const int* __restrict__ flag,
                          int* __restrict__ indeg) {
    int e = blockIdx.x * blockDim.x + threadIdx.x;
    int is64 = *flag;
    if (e < E) {
        int d = edge_val(ei, (long long)E + e, is64);
        atomicAdd(&indeg[d], 1);
    }
}

// ---------------- hierarchical exclusive scan (3 kernels) --------------------
__global__ __launch_bounds__(256) void partial_scan_k(const int* __restrict__ indeg,
                                                      int* __restrict__ rowptr,
                                                      float* __restrict__ dinv,
                                                      int* __restrict__ bsum, int n) {
    __shared__ int wsum[4];
    const int tid = threadIdx.x;
    const int i = blockIdx.x * 256 + tid;
    const int lane = tid & 63;
    const int wid = tid >> 6;
    int v = (i < n) ? indeg[i] : 0;
    if (i < n) dinv[i] = rsqrtf((float)(v + 1));  // +1 self loop
    int s = v;
#pragma unroll
    for (int off = 1; off < 64; off <<= 1) {
        int t = __shfl_up(s, off, 64);
        if (lane >= off) s += t;
    }
    if (lane == 63) wsum[wid] = s;
    __syncthreads();
    int woff = 0;
#pragma unroll
    for (int j = 0; j < 4; ++j)
        if (j < wid) woff += wsum[j];
    if (i < n) rowptr[i] = woff + s - v;  // block-local exclusive
    if (tid == 255) bsum[blockIdx.x] = woff + s;
}

__global__ __launch_bounds__(256) void scan_sums_k(const int* __restrict__ bsum,
                                                   int* __restrict__ boff, int nb) {
    __shared__ int wsum[4];
    const int tid = threadIdx.x;
    const int lane = tid & 63;
    const int wid = tid >> 6;
    int v = (tid < nb) ? bsum[tid] : 0;
    int s = v;
#pragma unroll
    for (int off = 1; off < 64; off <<= 1) {
        int t = __shfl_up(s, off, 64);
        if (lane >= off) s += t;
    }
    if (lane == 63) wsum[wid] = s;
    __syncthreads();
    int woff = 0;
#pragma unroll
    for (int j = 0; j < 4; ++j)
        if (j < wid) woff += wsum[j];
    boff[tid] = woff + s - v;  // exclusive
}

__global__ __launch_bounds__(256) void add_off_k(int* __restrict__ rowptr,
                                                 const int* __restrict__ boff,
                                                 int n, int total) {
    int i = blockIdx.x * 256 + threadIdx.x;
    if (i < n) rowptr[i] += boff[blockIdx.x];
    if (i == 0) rowptr[n] = total;
}

// per-bucket global cursor = rowptr at bucket start (bucket = 256-node range)
__global__ void init_gcur_k(const int* __restrict__ rowptr, int* __restrict__ gcursor, int N) {
    int b = threadIdx.x;  // one block of 256
    gcursor[b] = rowptr[min(b << 8, N)];
}

// ---------------- pass 1: partition edges into dst>>8 buckets ----------------
__global__ __launch_bounds__(256) void partition_k(const void* __restrict__ ei, int E,
                                                   const int* __restrict__ flag,
                                                   int* __restrict__ gcursor,
                                                   int2* __restrict__ tmp) {
    __shared__ int2 stage[CH];
    __shared__ int hist[256];
    __shared__ int off[256];
    __shared__ int rcur[256];
    __shared__ int goff[256];
    __shared__ int wsum[4];
    const int tid = threadIdx.x;
    const int base = blockIdx.x * CH;
    const int cnt = min(CH, E - base);
    const int is64 = *flag;
    hist[tid] = 0;
    __syncthreads();
    int sa[16], da[16];
    int ne = 0;
#pragma unroll
    for (int k = 0; k < 16; ++k) {
        int i = tid + k * 256;
        if (i < cnt) {
            sa[ne] = edge_val(ei, base + i, is64);
            da[ne] = edge_val(ei, (long long)E + base + i, is64);
            ne++;
        }
    }
    for (int k = 0; k < ne; ++k) atomicAdd(&hist[da[k] >> 8], 1);
    __syncthreads();
    {  // block-wide exclusive scan of hist -> off
        int v = hist[tid];
        int lane = tid & 63, wid = tid >> 6;
        int s = v;
#pragma unroll
        for (int o = 1; o < 64; o <<= 1) {
            int t = __shfl_up(s, o, 64);
            if (lane >= o) s += t;
        }
        if (lane == 63) wsum[wid] = s;
        __syncthreads();
        int w = 0;
#pragma unroll
        for (int j = 0; j < 4; ++j)
            if (j < wid) w += wsum[j];
        off[tid] = w + s - v;
        rcur[tid] = w + s - v;
    }
    __syncthreads();
    for (int k = 0; k < ne; ++k) {  // stage grouped by bucket
        int b = da[k] >> 8;
        int r = atomicAdd(&rcur[b], 1);
        stage[r] = make_int2(sa[k], da[k]);
    }
    __syncthreads();
    {  // grab contiguous global space per bucket
        int c = hist[tid];
        goff[tid] = (c > 0) ? atomicAdd(&gcursor[tid], c) : 0;
    }
    __syncthreads();
    for (int i = tid; i < cnt; i += 256) {  // coalesced-run dump
        int2 e = stage[i];
        int b = e.y >> 8;
        tmp[goff[b] + (i - off[b])] = e;
    }
}

// ---------------- pass 2: within-bucket scatter to final CSR slots -----------
__global__ __launch_bounds__(256) void bucket_fill_k(const int2* __restrict__ tmp,
                                                     const int* __restrict__ rowptr,
                                                     const float* __restrict__ dinv,
                                                     int2* __restrict__ edata, int N) {
    __shared__ int cur[256];
    __shared__ float dl[256];
    const int tid = threadIdx.x;
    const int node0 = blockIdx.x << 8;
    const int nn = min(256, N - node0);
    if (tid < nn) {
        cur[tid] = rowptr[node0 + tid];
        dl[tid] = dinv[node0 + tid];
    }
    __syncthreads();
    const int r0 = rowptr[node0];
    const int r1 = rowptr[node0 + nn];
    for (int i = r0 + tid; i < r1; i += 256) {
        int2 e = tmp[i];
        int li = e.y - node0;
        int pos = atomicAdd(&cur[li], 1);
        float wt = dinv[e.x] * dl[li];
        edata[pos] = make_int2(e.x, __float_as_int(wt));
    }
}

// ---------------- aggregation: one wave per node, lane = channel (64ch) ------
template <bool BIAS>
__global__ __launch_bounds__(256) void aggregate64_k(const float* __restrict__ feat,
                                                     const int* __restrict__ rowptr,
                                                     const int2* __restrict__ edata,
                                                     const float* __restrict__ dinv,
                                                     const float* __restrict__ bias,
                                                     float* __restrict__ out, int N) {
    int node = blockIdx.x * 4 + (threadIdx.x >> 6);
    int lane = threadIdx.x & 63;
    if (node >= N) return;
    float dn = dinv[node];
    float acc = feat[(size_t)node * 64 + lane] * (dn * dn);  // self loop
    int e = rowptr[node];
    int e1 = rowptr[node + 1];
    for (; e + 3 < e1; e += 4) {  // 4 gathers in flight
        int2 d0 = edata[e], d1 = edata[e + 1], d2 = edata[e + 2], d3 = edata[e + 3];
        float f0 = feat[(size_t)d0.x * 64 + lane];
        float f1 = feat[(size_t)d1.x * 64 + lane];
        float f2 = feat[(size_t)d2.x * 64 + lane];
        float f3 = feat[(size_t)d3.x * 64 + lane];
        acc = fmaf(__int_as_float(d0.y), f0, acc);
        acc = fmaf(__int_as_float(d1.y), f1, acc);
        acc = fmaf(__int_as_float(d2.y), f2, acc);
        acc = fmaf(__int_as_float(d3.y), f3, acc);
    }
    for (; e < e1; ++e) {
        int2 d = edata[e];
        acc = fmaf(__int_as_float(d.y), feat[(size_t)d.x * 64 + lane], acc);
    }
    if (BIAS) acc += bias[lane];
    out[(size_t)node * 64 + lane] = acc;
}

// ---------------- f32 GEMM: C[M,N] = A[M,K] @ B[K,N], optional bias+relu -----
template <int K, int N, bool RELU>
__global__ __launch_bounds__(256) void gemm_k(const float* __restrict__ A,
                                              const float* __restrict__ B,
                                              const float* __restrict__ bias,
                                              float* __restrict__ C, int M) {
    constexpr int BM = 64;
    constexpr int TM = 8;
    constexpr int TN = N / 32;
    __shared__ float As[BM * K];
    __shared__ float Bs[K * N];
    const int tid = threadIdx.x;
    const int row0 = blockIdx.x * BM;

    {
        const float4* B4 = (const float4*)B;
        float4* Bs4 = (float4*)Bs;
        for (int i = tid; i < K * N / 4; i += 256) Bs4[i] = B4[i];
        float4* As4 = (float4*)As;
        for (int i = tid; i < BM * K / 4; i += 256) {
            int idx = i * 4;
            int r = idx / K;
            int gr = row0 + r;
            float4 v = make_float4(0.f, 0.f, 0.f, 0.f);
            if (gr < M) v = *(const float4*)(A + (size_t)gr * K + (idx & (K - 1)));
            As4[i] = v;
        }
    }
    __syncthreads();

    const int rg = tid >> 5;  // 0..7
    const int cg = tid & 31;  // 0..31
    float acc[TM][TN];
#pragma unroll
    for (int i = 0; i < TM; ++i)
#pragma unroll
        for (int j = 0; j < TN; ++j) acc[i][j] = 0.f;

#pragma unroll 4
    for (int k = 0; k < K; ++k) {
        float a[TM], b[TN];
#pragma unroll
        for (int i = 0; i < TM; ++i) a[i] = As[(rg * TM + i) * K + k];
#pragma unroll
        for (int j = 0; j < TN; ++j) b[j] = Bs[k * N + cg * TN + j];
#pragma unroll
        for (int i = 0; i < TM; ++i)
#pragma unroll
            for (int j = 0; j < TN; ++j) acc[i][j] = fmaf(a[i], b[j], acc[i][j]);
    }

    float bb[TN];
    if (RELU) {
#pragma unroll
        for (int j = 0; j < TN; ++j) bb[j] = bias[cg * TN + j];
    }
#pragma unroll
    for (int i = 0; i < TM; ++i) {
        int r = row0 + rg * TM + i;
        if (r < M) {
#pragma unroll
            for (int j = 0; j < TN; ++j) {
                float v = acc[i][j];
                if (RELU) v = fmaxf(v + bb[j], 0.f);
                C[(size_t)r * N + cg * TN + j] = v;
            }
        }
    }
}

// ---------------- launch -----------------------------------------------------
extern "C" void kernel_launch(void* const* d_in, const int* in_sizes, int n_in,
                              void* d_out, int out_size, void* d_ws, size_t ws_size,
                              hipStream_t stream) {
    (void)n_in; (void)out_size; (void)ws_size;
    const float* x  = (const float*)d_in[0];
    const void*  ei = d_in[1];
    const float* W1 = (const float*)d_in[2];
    const float* b1 = (const float*)d_in[3];
    const float* W2 = (const float*)d_in[4];
    const float* b2 = (const float*)d_in[5];
    float* out = (float*)d_out;
    const int N = in_sizes[0] / IN_C;   // 50000
    const int E = in_sizes[1] / 2;      // 800000
    const int NB = (N + 255) / 256;     // scan blocks / buckets (196)
    const int PB = (E + CH - 1) / CH;   // partition blocks (196)

    char* p = (char*)d_ws;
    auto take = [&](size_t bytes) {
        char* r = p;
        p += (bytes + 255) & ~(size_t)255;
        return r;
    };
    int*   indeg   = (int*)take((size_t)N * 4);   // memset region start
    int*   flag    = (int*)take(256);
    int*   rowptr  = (int*)take(((size_t)N + 1) * 4);
    float* dinv    = (float*)take((size_t)N * 4);
    int*   bsum    = (int*)take(1024);
    int*   boff    = (int*)take(1024);
    int*   gcursor = (int*)take(1024);
    int2*  edata   = (int2*)take((size_t)E * 8);
    float* agg1    = (float*)take((size_t)N * IN_C * 4);
    float* h       = (float*)take((size_t)N * HID_C * 4);
    float* hw2     = (float*)take((size_t)N * OUT_C * 4);
    int2*  tmp     = (int2*)agg1;  // alias: tmp COO dead before agg1 is written

    hipMemsetAsync(indeg, 0, (size_t)N * 4, stream);

    detect_i64<<<1, 64, 0, stream>>>((const unsigned int*)ei, flag);
    count_deg<<<(E + 255) / 256, 256, 0, stream>>>(ei, E, flag, indeg);
    partial_scan_k<<<NB, 256, 0, stream>>>(indeg, rowptr, dinv, bsum, N);
    scan_sums_k<<<1, 256, 0, stream>>>(bsum, boff, NB);
    add_off_k<<<NB, 256, 0, stream>>>(rowptr, boff, N, E);
    init_gcur_k<<<1, 256, 0, stream>>>(rowptr, gcursor, N);
    partition_k<<<PB, 256, 0, stream>>>(ei, E, flag, gcursor, tmp);
    bucket_fill_k<<<NB, 256, 0, stream>>>(tmp, rowptr, dinv, edata, N);

    // layer 1: agg1 = A_hat x ; h = relu(agg1 @ W1 + b1)
    aggregate64_k<false><<<(N + 3) / 4, 256, 0, stream>>>(x, rowptr, edata, dinv, nullptr, agg1, N);
    gemm_k<IN_C, HID_C, true><<<(N + 63) / 64, 256, 0, stream>>>(agg1, W1, b1, h, N);

    // layer 2: hw2 = h @ W2 ; out = A_hat hw2 + b2
    gemm_k<HID_C, OUT_C, false><<<(N + 63) / 64, 256, 0, stream>>>(h, W2, nullptr, hw2, N);
    aggregate64_k<true><<<(N + 3) / 4, 256, 0, stream>>>(hw2, rowptr, edata, dinv, b2, out, N);
}

// Round 5
// 198.361 us; speedup vs baseline: 1.2758x; 1.0172x over previous
//
#include <hip/hip_runtime.h>
#include <cstdint>

// GCN 2-layer forward on MI355X.
// Layer 1: h = relu((A_hat x) W1 + b1)   -- aggregate at 64ch, then GEMM 64->128
// Layer 2: out = A_hat (h W2) + b2       -- GEMM 128->64, then aggregate at 64ch
// CSR-by-dst built per launch: init(zero+detect) -> histogram -> hierarchical
// scan -> 2-pass bucketed fill. No hipMemsetAsync in the graph (rocclr fill
// kernel measured 44us for 200KB -- replaced by init_k).

#define IN_C 64
#define HID_C 128
#define OUT_C 64
#define CH 4096  // edges per partition block

// ---------------- init: zero indeg + detect edge dtype -----------------------
__global__ __launch_bounds__(256) void init_k(const unsigned int* __restrict__ ei,
                                              int* __restrict__ flag,
                                              int* __restrict__ indeg, int N) {
    int i = blockIdx.x * 256 + threadIdx.x;
    if (i < N) indeg[i] = 0;
    if (i == 0) {
        int is64 = 1;
#pragma unroll
        for (int k = 0; k < 16; ++k) is64 &= (ei[2 * k + 1] == 0u) ? 1 : 0;
        *flag = is64;  // values < 50000 -> int64 layout has all-zero high dwords
    }
}

__device__ __forceinline__ int edge_val(const void* ei, long long idx, int is64) {
    if (is64) return (int)((const long long*)ei)[idx];
    return ((const int*)ei)[idx];
}

// ---------------- degree histogram -------------------------------------------
__global__ void count_deg(const void* __restrict__ ei, int E, const int* __restrict__ flag,
                          int* __restrict__ indeg) {
    int e = blockIdx.x * blockDim.x + threadIdx.x;
    int is64 = *flag;
    if (e < E) {
        int d = edge_val(ei, (long long)E + e, is64);
        atomicAdd(&indeg[d], 1);
    }
}

// ---------------- hierarchical exclusive scan (3 kernels) --------------------
__global__ __launch_bounds__(256) void partial_scan_k(const int* __restrict__ indeg,
                                                      int* __restrict__ rowptr,
                                                      float* __restrict__ dinv,
                                                      int* __restrict__ bsum, int n) {
    __shared__ int wsum[4];
    const int tid = threadIdx.x;
    const int i = blockIdx.x * 256 + tid;
    const int lane = tid & 63;
    const int wid = tid >> 6;
    int v = (i < n) ? indeg[i] : 0;
    if (i < n) dinv[i] = rsqrtf((float)(v + 1));  // +1 self loop
    int s = v;
#pragma unroll
    for (int off = 1; off < 64; off <<= 1) {
        int t = __shfl_up(s, off, 64);
        if (lane >= off) s += t;
    }
    if (lane == 63) wsum[wid] = s;
    __syncthreads();
    int woff = 0;
#pragma unroll
    for (int j = 0; j < 4; ++j)
        if (j < wid) woff += wsum[j];
    if (i < n) rowptr[i] = woff + s - v;  // block-local exclusive
    if (tid == 255) bsum[blockIdx.x] = woff + s;
}

__global__ __launch_bounds__(256) void scan_sums_k(const int* __restrict__ bsum,
                                                   int* __restrict__ boff, int nb) {
    __shared__ int wsum[4];
    const int tid = threadIdx.x;
    const int lane = tid & 63;
    const int wid = tid >> 6;
    int v = (tid < nb) ? bsum[tid] : 0;
    int s = v;
#pragma unroll
    for (int off = 1; off < 64; off <<= 1) {
        int t = __shfl_up(s, off, 64);
        if (lane >= off) s += t;
    }
    if (lane == 63) wsum[wid] = s;
    __syncthreads();
    int woff = 0;
#pragma unroll
    for (int j = 0; j < 4; ++j)
        if (j < wid) woff += wsum[j];
    boff[tid] = woff + s - v;  // exclusive
}

// finalize rowptr; also emit per-bucket global cursor (bucket = 256-node range)
__global__ __launch_bounds__(256) void add_off_k(int* __restrict__ rowptr,
                                                 const int* __restrict__ boff,
                                                 int* __restrict__ gcursor,
                                                 int n, int total) {
    int i = blockIdx.x * 256 + threadIdx.x;
    if (i < n) {
        int v = rowptr[i] + boff[blockIdx.x];
        rowptr[i] = v;
        if ((i & 255) == 0) gcursor[i >> 8] = v;
    }
    if (i == 0) rowptr[n] = total;
}

// ---------------- pass 1: partition edges into dst>>8 buckets ----------------
__global__ __launch_bounds__(256) void partition_k(const void* __restrict__ ei, int E,
                                                   const int* __restrict__ flag,
                                                   int* __restrict__ gcursor,
                                                   int2* __restrict__ tmp) {
    __shared__ int2 stage[CH];
    __shared__ int hist[256];
    __shared__ int off[256];
    __shared__ int rcur[256];
    __shared__ int goff[256];
    __shared__ int wsum[4];
    const int tid = threadIdx.x;
    const int base = blockIdx.x * CH;
    const int cnt = min(CH, E - base);
    const int is64 = *flag;
    hist[tid] = 0;
    __syncthreads();
    int sa[16], da[16];
    int ne = 0;
#pragma unroll
    for (int k = 0; k < 16; ++k) {
        int i = tid + k * 256;
        if (i < cnt) {
            sa[ne] = edge_val(ei, base + i, is64);
            da[ne] = edge_val(ei, (long long)E + base + i, is64);
            ne++;
        }
    }
    for (int k = 0; k < ne; ++k) atomicAdd(&hist[da[k] >> 8], 1);
    __syncthreads();
    {  // block-wide exclusive scan of hist -> off
        int v = hist[tid];
        int lane = tid & 63, wid = tid >> 6;
        int s = v;
#pragma unroll
        for (int o = 1; o < 64; o <<= 1) {
            int t = __shfl_up(s, o, 64);
            if (lane >= o) s += t;
        }
        if (lane == 63) wsum[wid] = s;
        __syncthreads();
        int w = 0;
#pragma unroll
        for (int j = 0; j < 4; ++j)
            if (j < wid) w += wsum[j];
        off[tid] = w + s - v;
        rcur[tid] = w + s - v;
    }
    __syncthreads();
    for (int k = 0; k < ne; ++k) {  // stage grouped by bucket
        int b = da[k] >> 8;
        int r = atomicAdd(&rcur[b], 1);
        stage[r] = make_int2(sa[k], da[k]);
    }
    __syncthreads();
    {  // grab contiguous global space per bucket
        int c = hist[tid];
        goff[tid] = (c > 0) ? atomicAdd(&gcursor[tid], c) : 0;
    }
    __syncthreads();
    for (int i = tid; i < cnt; i += 256) {  // coalesced-run dump
        int2 e = stage[i];
        int b = e.y >> 8;
        tmp[goff[b] + (i - off[b])] = e;
    }
}

// ---------------- pass 2: within-bucket scatter to final CSR slots -----------
__global__ __launch_bounds__(256) void bucket_fill_k(const int2* __restrict__ tmp,
                                                     const int* __restrict__ rowptr,
                                                     const float* __restrict__ dinv,
                                                     int2* __restrict__ edata, int N) {
    __shared__ int cur[256];
    __shared__ float dl[256];
    const int tid = threadIdx.x;
    const int node0 = blockIdx.x << 8;
    const int nn = min(256, N - node0);
    if (tid < nn) {
        cur[tid] = rowptr[node0 + tid];
        dl[tid] = dinv[node0 + tid];
    }
    __syncthreads();
    const int r0 = rowptr[node0];
    const int r1 = rowptr[node0 + nn];
    for (int i = r0 + tid; i < r1; i += 256) {
        int2 e = tmp[i];
        int li = e.y - node0;
        int pos = atomicAdd(&cur[li], 1);
        float wt = dinv[e.x] * dl[li];
        edata[pos] = make_int2(e.x, __float_as_int(wt));
    }
}

// ---------------- aggregation: one wave per node, lane = channel (64ch) ------
template <bool BIAS>
__global__ __launch_bounds__(256) void aggregate64_k(const float* __restrict__ feat,
                                                     const int* __restrict__ rowptr,
                                                     const int2* __restrict__ edata,
                                                     const float* __restrict__ dinv,
                                                     const float* __restrict__ bias,
                                                     float* __restrict__ out, int N) {
    int node = blockIdx.x * 4 + (threadIdx.x >> 6);
    int lane = threadIdx.x & 63;
    if (node >= N) return;
    float dn = dinv[node];
    float acc = feat[(size_t)node * 64 + lane] * (dn * dn);  // self loop
    int e = rowptr[node];
    int e1 = rowptr[node + 1];
    for (; e + 3 < e1; e += 4) {  // 4 gathers in flight
        int2 d0 = edata[e], d1 = edata[e + 1], d2 = edata[e + 2], d3 = edata[e + 3];
        float f0 = feat[(size_t)d0.x * 64 + lane];
        float f1 = feat[(size_t)d1.x * 64 + lane];
        float f2 = feat[(size_t)d2.x * 64 + lane];
        float f3 = feat[(size_t)d3.x * 64 + lane];
        acc = fmaf(__int_as_float(d0.y), f0, acc);
        acc = fmaf(__int_as_float(d1.y), f1, acc);
        acc = fmaf(__int_as_float(d2.y), f2, acc);
        acc = fmaf(__int_as_float(d3.y), f3, acc);
    }
    for (; e < e1; ++e) {
        int2 d = edata[e];
        acc = fmaf(__int_as_float(d.y), feat[(size_t)d.x * 64 + lane], acc);
    }
    if (BIAS) acc += bias[lane];
    out[(size_t)node * 64 + lane] = acc;
}

// ---------------- f32 GEMM: C[M,N] = A[M,K] @ B[K,N], optional bias+relu -----
template <int K, int N, bool RELU>
__global__ __launch_bounds__(256) void gemm_k(const float* __restrict__ A,
                                              const float* __restrict__ B,
                                              const float* __restrict__ bias,
                                              float* __restrict__ C, int M) {
    constexpr int BM = 64;
    constexpr int TM = 8;
    constexpr int TN = N / 32;
    __shared__ float As[BM * K];
    __shared__ float Bs[K * N];
    const int tid = threadIdx.x;
    const int row0 = blockIdx.x * BM;

    {
        const float4* B4 = (const float4*)B;
        float4* Bs4 = (float4*)Bs;
        for (int i = tid; i < K * N / 4; i += 256) Bs4[i] = B4[i];
        float4* As4 = (float4*)As;
        for (int i = tid; i < BM * K / 4; i += 256) {
            int idx = i * 4;
            int r = idx / K;
            int gr = row0 + r;
            float4 v = make_float4(0.f, 0.f, 0.f, 0.f);
            if (gr < M) v = *(const float4*)(A + (size_t)gr * K + (idx & (K - 1)));
            As4[i] = v;
        }
    }
    __syncthreads();

    const int rg = tid >> 5;  // 0..7
    const int cg = tid & 31;  // 0..31
    float acc[TM][TN];
#pragma unroll
    for (int i = 0; i < TM; ++i)
#pragma unroll
        for (int j = 0; j < TN; ++j) acc[i][j] = 0.f;

#pragma unroll 4
    for (int k = 0; k < K; ++k) {
        float a[TM], b[TN];
#pragma unroll
        for (int i = 0; i < TM; ++i) a[i] = As[(rg * TM + i) * K + k];
#pragma unroll
        for (int j = 0; j < TN; ++j) b[j] = Bs[k * N + cg * TN + j];
#pragma unroll
        for (int i = 0; i < TM; ++i)
#pragma unroll
            for (int j = 0; j < TN; ++j) acc[i][j] = fmaf(a[i], b[j], acc[i][j]);
    }

    float bb[TN];
    if (RELU) {
#pragma unroll
        for (int j = 0; j < TN; ++j) bb[j] = bias[cg * TN + j];
    }
#pragma unroll
    for (int i = 0; i < TM; ++i) {
        int r = row0 + rg * TM + i;
        if (r < M) {
#pragma unroll
            for (int j = 0; j < TN; ++j) {
                float v = acc[i][j];
                if (RELU) v = fmaxf(v + bb[j], 0.f);
                C[(size_t)r * N + cg * TN + j] = v;
            }
        }
    }
}

// ---------------- launch -----------------------------------------------------
extern "C" void kernel_launch(void* const* d_in, const int* in_sizes, int n_in,
                              void* d_out, int out_size, void* d_ws, size_t ws_size,
                              hipStream_t stream) {
    (void)n_in; (void)out_size; (void)ws_size;
    const float* x  = (const float*)d_in[0];
    const void*  ei = d_in[1];
    const float* W1 = (const float*)d_in[2];
    const float* b1 = (const float*)d_in[3];
    const float* W2 = (const float*)d_in[4];
    const float* b2 = (const float*)d_in[5];
    float* out = (float*)d_out;
    const int N = in_sizes[0] / IN_C;   // 50000
    const int E = in_sizes[1] / 2;      // 800000
    const int NB = (N + 255) / 256;     // scan blocks / buckets (196)
    const int PB = (E + CH - 1) / CH;   // partition blocks (196)

    char* p = (char*)d_ws;
    auto take = [&](size_t bytes) {
        char* r = p;
        p += (bytes + 255) & ~(size_t)255;
        return r;
    };
    int*   indeg   = (int*)take((size_t)N * 4);
    int*   flag    = (int*)take(256);
    int*   rowptr  = (int*)take(((size_t)N + 1) * 4);
    float* dinv    = (float*)take((size_t)N * 4);
    int*   bsum    = (int*)take(1024);
    int*   boff    = (int*)take(1024);
    int*   gcursor = (int*)take(1024);
    int2*  edata   = (int2*)take((size_t)E * 8);
    float* agg1    = (float*)take((size_t)N * IN_C * 4);
    float* h       = (float*)take((size_t)N * HID_C * 4);
    float* hw2     = (float*)take((size_t)N * OUT_C * 4);
    int2*  tmp     = (int2*)agg1;  // alias: tmp COO dead before agg1 is written

    init_k<<<NB, 256, 0, stream>>>((const unsigned int*)ei, flag, indeg, N);
    count_deg<<<(E + 255) / 256, 256, 0, stream>>>(ei, E, flag, indeg);
    partial_scan_k<<<NB, 256, 0, stream>>>(indeg, rowptr, dinv, bsum, N);
    scan_sums_k<<<1, 256, 0, stream>>>(bsum, boff, NB);
    add_off_k<<<NB, 256, 0, stream>>>(rowptr, boff, gcursor, N, E);
    partition_k<<<PB, 256, 0, stream>>>(ei, E, flag, gcursor, tmp);
    bucket_fill_k<<<NB, 256, 0, stream>>>(tmp, rowptr, dinv, edata, N);

    // layer 1: agg1 = A_hat x ; h = relu(agg1 @ W1 + b1)
    aggregate64_k<false><<<(N + 3) / 4, 256, 0, stream>>>(x, rowptr, edata, dinv, nullptr, agg1, N);
    gemm_k<IN_C, HID_C, true><<<(N + 63) / 64, 256, 0, stream>>>(agg1, W1, b1, h, N);

    // layer 2: hw2 = h @ W2 ; out = A_hat hw2 + b2
    gemm_k<HID_C, OUT_C, false><<<(N + 63) / 64, 256, 0, stream>>>(h, W2, nullptr, hw2, N);
    aggregate64_k<true><<<(N + 3) / 4, 256, 0, stream>>>(hw2, rowptr, edata, dinv, b2, out, N);
}

// Round 8
// 179.979 us; speedup vs baseline: 1.4061x; 1.1021x over previous
//
#include <hip/hip_runtime.h>
#include <cstdint>

// GCN 2-layer forward on MI355X.
// Layer 1: h = relu((A_hat x) W1 + b1)   -- aggregate at 64ch, then GEMM 64->128
// Layer 2: out = A_hat (h W2) + b2       -- GEMM 128->64, then aggregate at 64ch
// CSR-by-dst built per launch: init -> histogram -> hierarchical scan -> 2-pass
// bucketed fill. Aggregation: 16 lanes x float4 per node (4 nodes/wave, 4-deep
// unroll -> 16 gathers in flight/wave; the old 1-wave-per-node version was
// latency-bound at 4 gathers in flight, 41us).

#define IN_C 64
#define HID_C 128
#define OUT_C 64
#define CH 4096  // edges per partition block

// ---------------- init: zero indeg + detect edge dtype -----------------------
__global__ __launch_bounds__(256) void init_k(const unsigned int* __restrict__ ei,
                                              int* __restrict__ flag,
                                              int* __restrict__ indeg, int N) {
    int i = blockIdx.x * 256 + threadIdx.x;
    if (i < N) indeg[i] = 0;
    if (i == 0) {
        int is64 = 1;
#pragma unroll
        for (int k = 0; k < 16; ++k) is64 &= (ei[2 * k + 1] == 0u) ? 1 : 0;
        *flag = is64;  // values < 50000 -> int64 layout has all-zero high dwords
    }
}

__device__ __forceinline__ int edge_val(const void* ei, long long idx, int is64) {
    if (is64) return (int)((const long long*)ei)[idx];
    return ((const int*)ei)[idx];
}

// ---------------- degree histogram -------------------------------------------
__global__ void count_deg(const void* __restrict__ ei, int E, const int* __restrict__ flag,
                          int* __restrict__ indeg) {
    int e = blockIdx.x * blockDim.x + threadIdx.x;
    int is64 = *flag;
    if (e < E) {
        int d = edge_val(ei, (long long)E + e, is64);
        atomicAdd(&indeg[d], 1);
    }
}

// ---------------- hierarchical exclusive scan (3 kernels) --------------------
__global__ __launch_bounds__(256) void partial_scan_k(const int* __restrict__ indeg,
                                                      int* __restrict__ rowptr,
                                                      float* __restrict__ dinv,
                                                      int* __restrict__ bsum, int n) {
    __shared__ int wsum[4];
    const int tid = threadIdx.x;
    const int i = blockIdx.x * 256 + tid;
    const int lane = tid & 63;
    const int wid = tid >> 6;
    int v = (i < n) ? indeg[i] : 0;
    if (i < n) dinv[i] = rsqrtf((float)(v + 1));  // +1 self loop
    int s = v;
#pragma unroll
    for (int off = 1; off < 64; off <<= 1) {
        int t = __shfl_up(s, off, 64);
        if (lane >= off) s += t;
    }
    if (lane == 63) wsum[wid] = s;
    __syncthreads();
    int woff = 0;
#pragma unroll
    for (int j = 0; j < 4; ++j)
        if (j < wid) woff += wsum[j];
    if (i < n) rowptr[i] = woff + s - v;  // block-local exclusive
    if (tid == 255) bsum[blockIdx.x] = woff + s;
}

__global__ __launch_bounds__(256) void scan_sums_k(const int* __restrict__ bsum,
                                                   int* __restrict__ boff, int nb) {
    __shared__ int wsum[4];
    const int tid = threadIdx.x;
    const int lane = tid & 63;
    const int wid = tid >> 6;
    int v = (tid < nb) ? bsum[tid] : 0;
    int s = v;
#pragma unroll
    for (int off = 1; off < 64; off <<= 1) {
        int t = __shfl_up(s, off, 64);
        if (lane >= off) s += t;
    }
    if (lane == 63) wsum[wid] = s;
    __syncthreads();
    int woff = 0;
#pragma unroll
    for (int j = 0; j < 4; ++j)
        if (j < wid) woff += wsum[j];
    boff[tid] = woff + s - v;  // exclusive
}

// finalize rowptr; also emit per-bucket global cursor (bucket = 256-node range)
__global__ __launch_bounds__(256) void add_off_k(int* __restrict__ rowptr,
                                                 const int* __restrict__ boff,
                                                 int* __restrict__ gcursor,
                                                 int n, int total) {
    int i = blockIdx.x * 256 + threadIdx.x;
    if (i < n) {
        int v = rowptr[i] + boff[blockIdx.x];
        rowptr[i] = v;
        if ((i & 255) == 0) gcursor[i >> 8] = v;
    }
    if (i == 0) rowptr[n] = total;
}

// ---------------- pass 1: partition edges into dst>>8 buckets ----------------
__global__ __launch_bounds__(256) void partition_k(const void* __restrict__ ei, int E,
                                                   const int* __restrict__ flag,
                                                   int* __restrict__ gcursor,
                                                   int2* __restrict__ tmp) {
    __shared__ int2 stage[CH];
    __shared__ int hist[256];
    __shared__ int off[256];
    __shared__ int rcur[256];
    __shared__ int goff[256];
    __shared__ int wsum[4];
    const int tid = threadIdx.x;
    const int base = blockIdx.x * CH;
    const int cnt = min(CH, E - base);
    const int is64 = *flag;
    hist[tid] = 0;
    __syncthreads();
    int sa[16], da[16];
    int ne = 0;
#pragma unroll
    for (int k = 0; k < 16; ++k) {
        int i = tid + k * 256;
        if (i < cnt) {
            sa[ne] = edge_val(ei, base + i, is64);
            da[ne] = edge_val(ei, (long long)E + base + i, is64);
            ne++;
        }
    }
    for (int k = 0; k < ne; ++k) atomicAdd(&hist[da[k] >> 8], 1);
    __syncthreads();
    {  // block-wide exclusive scan of hist -> off
        int v = hist[tid];
        int lane = tid & 63, wid = tid >> 6;
        int s = v;
#pragma unroll
        for (int o = 1; o < 64; o <<= 1) {
            int t = __shfl_up(s, o, 64);
            if (lane >= o) s += t;
        }
        if (lane == 63) wsum[wid] = s;
        __syncthreads();
        int w = 0;
#pragma unroll
        for (int j = 0; j < 4; ++j)
            if (j < wid) w += wsum[j];
        off[tid] = w + s - v;
        rcur[tid] = w + s - v;
    }
    __syncthreads();
    for (int k = 0; k < ne; ++k) {  // stage grouped by bucket
        int b = da[k] >> 8;
        int r = atomicAdd(&rcur[b], 1);
        stage[r] = make_int2(sa[k], da[k]);
    }
    __syncthreads();
    {  // grab contiguous global space per bucket
        int c = hist[tid];
        goff[tid] = (c > 0) ? atomicAdd(&gcursor[tid], c) : 0;
    }
    __syncthreads();
    for (int i = tid; i < cnt; i += 256) {  // coalesced-run dump
        int2 e = stage[i];
        int b = e.y >> 8;
        tmp[goff[b] + (i - off[b])] = e;
    }
}

// ---------------- pass 2: within-bucket scatter to final CSR slots -----------
__global__ __launch_bounds__(256) void bucket_fill_k(const int2* __restrict__ tmp,
                                                     const int* __restrict__ rowptr,
                                                     const float* __restrict__ dinv,
                                                     int2* __restrict__ edata, int N) {
    __shared__ int cur[256];
    __shared__ float dl[256];
    const int tid = threadIdx.x;
    const int node0 = blockIdx.x << 8;
    const int nn = min(256, N - node0);
    if (tid < nn) {
        cur[tid] = rowptr[node0 + tid];
        dl[tid] = dinv[node0 + tid];
    }
    __syncthreads();
    const int r0 = rowptr[node0];
    const int r1 = rowptr[node0 + nn];
    for (int i = r0 + tid; i < r1; i += 256) {
        int2 e = tmp[i];
        int li = e.y - node0;
        int pos = atomicAdd(&cur[li], 1);
        float wt = dinv[e.x] * dl[li];
        edata[pos] = make_int2(e.x, __float_as_int(wt));
    }
}

// ---------------- aggregation: 16 lanes x float4 per node, 16 nodes/block ----
template <bool BIAS>
__global__ __launch_bounds__(256) void aggregate4x_k(const float4* __restrict__ feat4,
                                                     const int* __restrict__ rowptr,
                                                     const int2* __restrict__ edata,
                                                     const float* __restrict__ dinv,
                                                     const float4* __restrict__ bias4,
                                                     float4* __restrict__ out4, int N) {
    const int tid = threadIdx.x;
    const int node = blockIdx.x * 16 + (tid >> 4);
    const int t = tid & 15;  // 4 channels per lane: [4t .. 4t+3]
    if (node >= N) return;
    float dn = dinv[node];
    float sl = dn * dn;
    float4 acc = feat4[(size_t)node * 16 + t];  // self loop
    acc.x *= sl; acc.y *= sl; acc.z *= sl; acc.w *= sl;
    int e = rowptr[node];
    const int e1 = rowptr[node + 1];
    for (; e + 4 <= e1; e += 4) {  // 4 edges x 4 groups = 16 gathers/wave in flight
        int2 d0 = edata[e], d1 = edata[e + 1], d2 = edata[e + 2], d3 = edata[e + 3];
        float4 f0 = feat4[(size_t)d0.x * 16 + t];
        float4 f1 = feat4[(size_t)d1.x * 16 + t];
        float4 f2 = feat4[(size_t)d2.x * 16 + t];
        float4 f3 = feat4[(size_t)d3.x * 16 + t];
        float w0 = __int_as_float(d0.y), w1 = __int_as_float(d1.y);
        float w2 = __int_as_float(d2.y), w3 = __int_as_float(d3.y);
        acc.x = fmaf(w0, f0.x, acc.x); acc.y = fmaf(w0, f0.y, acc.y);
        acc.z = fmaf(w0, f0.z, acc.z); acc.w = fmaf(w0, f0.w, acc.w);
        acc.x = fmaf(w1, f1.x, acc.x); acc.y = fmaf(w1, f1.y, acc.y);
        acc.z = fmaf(w1, f1.z, acc.z); acc.w = fmaf(w1, f1.w, acc.w);
        acc.x = fmaf(w2, f2.x, acc.x); acc.y = fmaf(w2, f2.y, acc.y);
        acc.z = fmaf(w2, f2.z, acc.z); acc.w = fmaf(w2, f2.w, acc.w);
        acc.x = fmaf(w3, f3.x, acc.x); acc.y = fmaf(w3, f3.y, acc.y);
        acc.z = fmaf(w3, f3.z, acc.z); acc.w = fmaf(w3, f3.w, acc.w);
    }
    if (e + 2 <= e1) {
        int2 d0 = edata[e], d1 = edata[e + 1];
        float4 f0 = feat4[(size_t)d0.x * 16 + t];
        float4 f1 = feat4[(size_t)d1.x * 16 + t];
        float w0 = __int_as_float(d0.y), w1 = __int_as_float(d1.y);
        acc.x = fmaf(w0, f0.x, acc.x); acc.y = fmaf(w0, f0.y, acc.y);
        acc.z = fmaf(w0, f0.z, acc.z); acc.w = fmaf(w0, f0.w, acc.w);
        acc.x = fmaf(w1, f1.x, acc.x); acc.y = fmaf(w1, f1.y, acc.y);
        acc.z = fmaf(w1, f1.z, acc.z); acc.w = fmaf(w1, f1.w, acc.w);
        e += 2;
    }
    if (e < e1) {
        int2 d0 = edata[e];
        float4 f0 = feat4[(size_t)d0.x * 16 + t];
        float w0 = __int_as_float(d0.y);
        acc.x = fmaf(w0, f0.x, acc.x); acc.y = fmaf(w0, f0.y, acc.y);
        acc.z = fmaf(w0, f0.z, acc.z); acc.w = fmaf(w0, f0.w, acc.w);
    }
    if (BIAS) {
        float4 b = bias4[t];
        acc.x += b.x; acc.y += b.y; acc.z += b.z; acc.w += b.w;
    }
    out4[(size_t)node * 16 + t] = acc;
}

// ---------------- f32 GEMM: C[M,N] = A[M,K] @ B[K,N], optional bias+relu -----
template <int K, int N, bool RELU>
__global__ __launch_bounds__(256) void gemm_k(const float* __restrict__ A,
                                              const float* __restrict__ B,
                                              const float* __restrict__ bias,
                                              float* __restrict__ C, int M) {
    constexpr int BM = 64;
    constexpr int TM = 8;
    constexpr int TN = N / 32;
    __shared__ float As[BM * K];
    __shared__ float Bs[K * N];
    const int tid = threadIdx.x;
    const int row0 = blockIdx.x * BM;

    {
        const float4* B4 = (const float4*)B;
        float4* Bs4 = (float4*)Bs;
        for (int i = tid; i < K * N / 4; i += 256) Bs4[i] = B4[i];
        float4* As4 = (float4*)As;
        for (int i = tid; i < BM * K / 4; i += 256) {
            int idx = i * 4;
            int r = idx / K;
            int gr = row0 + r;
            float4 v = make_float4(0.f, 0.f, 0.f, 0.f);
            if (gr < M) v = *(const float4*)(A + (size_t)gr * K + (idx & (K - 1)));
            As4[i] = v;
        }
    }
    __syncthreads();

    const int rg = tid >> 5;  // 0..7
    const int cg = tid & 31;  // 0..31
    float acc[TM][TN];
#pragma unroll
    for (int i = 0; i < TM; ++i)
#pragma unroll
        for (int j = 0; j < TN; ++j) acc[i][j] = 0.f;

#pragma unroll 4
    for (int k = 0; k < K; ++k) {
        float a[TM], b[TN];
#pragma unroll
        for (int i = 0; i < TM; ++i) a[i] = As[(rg * TM + i) * K + k];
#pragma unroll
        for (int j = 0; j < TN; ++j) b[j] = Bs[k * N + cg * TN + j];
#pragma unroll
        for (int i = 0; i < TM; ++i)
#pragma unroll
            for (int j = 0; j < TN; ++j) acc[i][j] = fmaf(a[i], b[j], acc[i][j]);
    }

    float bb[TN];
    if (RELU) {
#pragma unroll
        for (int j = 0; j < TN; ++j) bb[j] = bias[cg * TN + j];
    }
#pragma unroll
    for (int i = 0; i < TM; ++i) {
        int r = row0 + rg * TM + i;
        if (r < M) {
#pragma unroll
            for (int j = 0; j < TN; ++j) {
                float v = acc[i][j];
                if (RELU) v = fmaxf(v + bb[j], 0.f);
                C[(size_t)r * N + cg * TN + j] = v;
            }
        }
    }
}

// ---------------- launch -----------------------------------------------------
extern "C" void kernel_launch(void* const* d_in, const int* in_sizes, int n_in,
                              void* d_out, int out_size, void* d_ws, size_t ws_size,
                              hipStream_t stream) {
    (void)n_in; (void)out_size; (void)ws_size;
    const float* x  = (const float*)d_in[0];
    const void*  ei = d_in[1];
    const float* W1 = (const float*)d_in[2];
    const float* b1 = (const float*)d_in[3];
    const float* W2 = (const float*)d_in[4];
    const float* b2 = (const float*)d_in[5];
    float* out = (float*)d_out;
    const int N = in_sizes[0] / IN_C;   // 50000
    const int E = in_sizes[1] / 2;      // 800000
    const int NB = (N + 255) / 256;     // scan blocks / buckets (196)
    const int PB = (E + CH - 1) / CH;   // partition blocks (196)

    char* p = (char*)d_ws;
    auto take = [&](size_t bytes) {
        char* r = p;
        p += (bytes + 255) & ~(size_t)255;
        return r;
    };
    int*   indeg   = (int*)take((size_t)N * 4);
    int*   flag    = (int*)take(256);
    int*   rowptr  = (int*)take(((size_t)N + 1) * 4);
    float* dinv    = (float*)take((size_t)N * 4);
    int*   bsum    = (int*)take(1024);
    int*   boff    = (int*)take(1024);
    int*   gcursor = (int*)take(1024);
    int2*  edata   = (int2*)take((size_t)E * 8);
    float* agg1    = (float*)take((size_t)N * IN_C * 4);
    float* h       = (float*)take((size_t)N * HID_C * 4);
    float* hw2     = (float*)take((size_t)N * OUT_C * 4);
    int2*  tmp     = (int2*)agg1;  // alias: tmp COO dead before agg1 is written

    init_k<<<NB, 256, 0, stream>>>((const unsigned int*)ei, flag, indeg, N);
    count_deg<<<(E + 255) / 256, 256, 0, stream>>>(ei, E, flag, indeg);
    partial_scan_k<<<NB, 256, 0, stream>>>(indeg, rowptr, dinv, bsum, N);
    scan_sums_k<<<1, 256, 0, stream>>>(bsum, boff, NB);
    add_off_k<<<NB, 256, 0, stream>>>(rowptr, boff, gcursor, N, E);
    partition_k<<<PB, 256, 0, stream>>>(ei, E, flag, gcursor, tmp);
    bucket_fill_k<<<NB, 256, 0, stream>>>(tmp, rowptr, dinv, edata, N);

    // layer 1: agg1 = A_hat x ; h = relu(agg1 @ W1 + b1)
    aggregate4x_k<false><<<(N + 15) / 16, 256, 0, stream>>>(
        (const float4*)x, rowptr, edata, dinv, nullptr, (float4*)agg1, N);
    gemm_k<IN_C, HID_C, true><<<(N + 63) / 64, 256, 0, stream>>>(agg1, W1, b1, h, N);

    // layer 2: hw2 = h @ W2 ; out = A_hat hw2 + b2
    gemm_k<HID_C, OUT_C, false><<<(N + 63) / 64, 256, 0, stream>>>(h, W2, nullptr, hw2, N);
    aggregate4x_k<true><<<(N + 15) / 16, 256, 0, stream>>>(
        (const float4*)hw2, rowptr, edata, dinv, (const float4*)b2, (float4*)out, N);
}

// Round 9
// 162.319 us; speedup vs baseline: 1.5591x; 1.1088x over previous
//
#include <hip/hip_runtime.h>
#include <cstdint>

// GCN 2-layer forward on MI355X.
// Layer 1: h = relu((A_hat x) W1 + b1)   -- aggregate at 64ch, then GEMM 64->128
// Layer 2: out = A_hat (h W2) + b2       -- GEMM 128->64 (bf16 out), aggregate 64ch
// CSR-by-dst built per launch: init(+x->bf16) -> histogram -> hierarchical scan
// -> 2-pass bucketed fill. Aggregations gather a bf16 feature table (128B/row =
// 1 cache line; f32 rows were 256B/2 lines and ran at the ~6.4TB/s gather
// ceiling, 32us each). f32 accumulate throughout; absmax budget 9.96e-3.

#define IN_C 64
#define HID_C 128
#define OUT_C 64
#define CH 4096  // edges per partition block

__device__ __forceinline__ unsigned short f2bf(float f) {  // RNE
    unsigned int u = __float_as_uint(f);
    return (unsigned short)((u + 0x7FFFu + ((u >> 16) & 1u)) >> 16);
}
__device__ __forceinline__ float bf2f(unsigned int hi16) {  // hi16 in low bits
    return __uint_as_float(hi16 << 16);
}

__device__ __forceinline__ int edge_val(const void* ei, long long idx, int is64) {
    if (is64) return (int)((const long long*)ei)[idx];
    return ((const int*)ei)[idx];
}

// ---------------- init: zero indeg + detect dtype + x -> bf16 ----------------
__global__ __launch_bounds__(256) void init_conv_k(const unsigned int* __restrict__ ei,
                                                   int* __restrict__ flag,
                                                   int* __restrict__ indeg,
                                                   const float4* __restrict__ x4,
                                                   uint2* __restrict__ xbf2, int N, int NC4) {
    int i = blockIdx.x * 256 + threadIdx.x;
    if (i < NC4) {
        float4 v = x4[i];
        uint2 o;
        o.x = (unsigned int)f2bf(v.x) | ((unsigned int)f2bf(v.y) << 16);
        o.y = (unsigned int)f2bf(v.z) | ((unsigned int)f2bf(v.w) << 16);
        xbf2[i] = o;
    }
    if (i < N) indeg[i] = 0;
    if (i == 0) {
        int is64 = 1;
#pragma unroll
        for (int k = 0; k < 16; ++k) is64 &= (ei[2 * k + 1] == 0u) ? 1 : 0;
        *flag = is64;  // values < 50000 -> int64 layout has all-zero high dwords
    }
}

// ---------------- degree histogram -------------------------------------------
__global__ void count_deg(const void* __restrict__ ei, int E, const int* __restrict__ flag,
                          int* __restrict__ indeg) {
    int e = blockIdx.x * blockDim.x + threadIdx.x;
    int is64 = *flag;
    if (e < E) {
        int d = edge_val(ei, (long long)E + e, is64);
        atomicAdd(&indeg[d], 1);
    }
}

// ---------------- hierarchical exclusive scan (3 kernels) --------------------
__global__ __launch_bounds__(256) void partial_scan_k(const int* __restrict__ indeg,
                                                      int* __restrict__ rowptr,
                                                      float* __restrict__ dinv,
                                                      int* __restrict__ bsum, int n) {
    __shared__ int wsum[4];
    const int tid = threadIdx.x;
    const int i = blockIdx.x * 256 + tid;
    const int lane = tid & 63;
    const int wid = tid >> 6;
    int v = (i < n) ? indeg[i] : 0;
    if (i < n) dinv[i] = rsqrtf((float)(v + 1));  // +1 self loop
    int s = v;
#pragma unroll
    for (int off = 1; off < 64; off <<= 1) {
        int t = __shfl_up(s, off, 64);
        if (lane >= off) s += t;
    }
    if (lane == 63) wsum[wid] = s;
    __syncthreads();
    int woff = 0;
#pragma unroll
    for (int j = 0; j < 4; ++j)
        if (j < wid) woff += wsum[j];
    if (i < n) rowptr[i] = woff + s - v;  // block-local exclusive
    if (tid == 255) bsum[blockIdx.x] = woff + s;
}

__global__ __launch_bounds__(256) void scan_sums_k(const int* __restrict__ bsum,
                                                   int* __restrict__ boff, int nb) {
    __shared__ int wsum[4];
    const int tid = threadIdx.x;
    const int lane = tid & 63;
    const int wid = tid >> 6;
    int v = (tid < nb) ? bsum[tid] : 0;
    int s = v;
#pragma unroll
    for (int off = 1; off < 64; off <<= 1) {
        int t = __shfl_up(s, off, 64);
        if (lane >= off) s += t;
    }
    if (lane == 63) wsum[wid] = s;
    __syncthreads();
    int woff = 0;
#pragma unroll
    for (int j = 0; j < 4; ++j)
        if (j < wid) woff += wsum[j];
    boff[tid] = woff + s - v;  // exclusive
}

// finalize rowptr; also emit per-bucket global cursor (bucket = 256-node range)
__global__ __launch_bounds__(256) void add_off_k(int* __restrict__ rowptr,
                                                 const int* __restrict__ boff,
                                                 int* __restrict__ gcursor,
                                                 int n, int total) {
    int i = blockIdx.x * 256 + threadIdx.x;
    if (i < n) {
        int v = rowptr[i] + boff[blockIdx.x];
        rowptr[i] = v;
        if ((i & 255) == 0) gcursor[i >> 8] = v;
    }
    if (i == 0) rowptr[n] = total;
}

// ---------------- pass 1: partition edges into dst>>8 buckets ----------------
__global__ __launch_bounds__(256) void partition_k(const void* __restrict__ ei, int E,
                                                   const int* __restrict__ flag,
                                                   int* __restrict__ gcursor,
                                                   int2* __restrict__ tmp) {
    __shared__ int2 stage[CH];
    __shared__ int hist[256];
    __shared__ int off[256];
    __shared__ int rcur[256];
    __shared__ int goff[256];
    __shared__ int wsum[4];
    const int tid = threadIdx.x;
    const int base = blockIdx.x * CH;
    const int cnt = min(CH, E - base);
    const int is64 = *flag;
    hist[tid] = 0;
    __syncthreads();
    int sa[16], da[16];
    int ne = 0;
#pragma unroll
    for (int k = 0; k < 16; ++k) {
        int i = tid + k * 256;
        if (i < cnt) {
            sa[ne] = edge_val(ei, base + i, is64);
            da[ne] = edge_val(ei, (long long)E + base + i, is64);
            ne++;
        }
    }
    for (int k = 0; k < ne; ++k) atomicAdd(&hist[da[k] >> 8], 1);
    __syncthreads();
    {  // block-wide exclusive scan of hist -> off
        int v = hist[tid];
        int lane = tid & 63, wid = tid >> 6;
        int s = v;
#pragma unroll
        for (int o = 1; o < 64; o <<= 1) {
            int t = __shfl_up(s, o, 64);
            if (lane >= o) s += t;
        }
        if (lane == 63) wsum[wid] = s;
        __syncthreads();
        int w = 0;
#pragma unroll
        for (int j = 0; j < 4; ++j)
            if (j < wid) w += wsum[j];
        off[tid] = w + s - v;
        rcur[tid] = w + s - v;
    }
    __syncthreads();
    for (int k = 0; k < ne; ++k) {  // stage grouped by bucket
        int b = da[k] >> 8;
        int r = atomicAdd(&rcur[b], 1);
        stage[r] = make_int2(sa[k], da[k]);
    }
    __syncthreads();
    {  // grab contiguous global space per bucket
        int c = hist[tid];
        goff[tid] = (c > 0) ? atomicAdd(&gcursor[tid], c) : 0;
    }
    __syncthreads();
    for (int i = tid; i < cnt; i += 256) {  // coalesced-run dump
        int2 e = stage[i];
        int b = e.y >> 8;
        tmp[goff[b] + (i - off[b])] = e;
    }
}

// ---------------- pass 2: within-bucket scatter to final CSR slots -----------
__global__ __launch_bounds__(256) void bucket_fill_k(const int2* __restrict__ tmp,
                                                     const int* __restrict__ rowptr,
                                                     const float* __restrict__ dinv,
                                                     int2* __restrict__ edata, int N) {
    __shared__ int cur[256];
    __shared__ float dl[256];
    const int tid = threadIdx.x;
    const int node0 = blockIdx.x << 8;
    const int nn = min(256, N - node0);
    if (tid < nn) {
        cur[tid] = rowptr[node0 + tid];
        dl[tid] = dinv[node0 + tid];
    }
    __syncthreads();
    const int r0 = rowptr[node0];
    const int r1 = rowptr[node0 + nn];
    for (int i = r0 + tid; i < r1; i += 256) {
        int2 e = tmp[i];
        int li = e.y - node0;
        int pos = atomicAdd(&cur[li], 1);
        float wt = dinv[e.x] * dl[li];
        edata[pos] = make_int2(e.x, __float_as_int(wt));
    }
}

// ------- aggregation over bf16 table: 16 lanes x uint2(4 bf16) per node ------
template <bool BIAS>
__global__ __launch_bounds__(256) void aggregate_bf16_k(const uint2* __restrict__ feat2,
                                                        const int* __restrict__ rowptr,
                                                        const int2* __restrict__ edata,
                                                        const float* __restrict__ dinv,
                                                        const float4* __restrict__ bias4,
                                                        float4* __restrict__ out4, int N) {
    const int tid = threadIdx.x;
    const int node = blockIdx.x * 16 + (tid >> 4);
    const int t = tid & 15;  // 4 channels per lane: [4t .. 4t+3]
    if (node >= N) return;
    float dn = dinv[node];
    float sl = dn * dn;
    uint2 sv = feat2[(size_t)node * 16 + t];  // self loop row
    float4 acc;
    acc.x = bf2f(sv.x & 0xFFFF) * sl;
    acc.y = bf2f(sv.x >> 16) * sl;
    acc.z = bf2f(sv.y & 0xFFFF) * sl;
    acc.w = bf2f(sv.y >> 16) * sl;
    int e = rowptr[node];
    const int e1 = rowptr[node + 1];
#define ACC_EDGE(V, W)                                         \
    acc.x = fmaf((W), bf2f((V).x & 0xFFFF), acc.x);            \
    acc.y = fmaf((W), bf2f((V).x >> 16), acc.y);               \
    acc.z = fmaf((W), bf2f((V).y & 0xFFFF), acc.z);            \
    acc.w = fmaf((W), bf2f((V).y >> 16), acc.w);
    for (; e + 4 <= e1; e += 4) {  // 4 edges in flight per lane
        int2 d0 = edata[e], d1 = edata[e + 1], d2 = edata[e + 2], d3 = edata[e + 3];
        uint2 f0 = feat2[(size_t)d0.x * 16 + t];
        uint2 f1 = feat2[(size_t)d1.x * 16 + t];
        uint2 f2 = feat2[(size_t)d2.x * 16 + t];
        uint2 f3 = feat2[(size_t)d3.x * 16 + t];
        ACC_EDGE(f0, __int_as_float(d0.y));
        ACC_EDGE(f1, __int_as_float(d1.y));
        ACC_EDGE(f2, __int_as_float(d2.y));
        ACC_EDGE(f3, __int_as_float(d3.y));
    }
    for (; e < e1; ++e) {
        int2 d0 = edata[e];
        uint2 f0 = feat2[(size_t)d0.x * 16 + t];
        ACC_EDGE(f0, __int_as_float(d0.y));
    }
#undef ACC_EDGE
    if (BIAS) {
        float4 b = bias4[t];
        acc.x += b.x; acc.y += b.y; acc.z += b.z; acc.w += b.w;
    }
    out4[(size_t)node * 16 + t] = acc;
}

// ------- f32 GEMM: C[M,N] = A[M,K] @ B[K,N]; optional bias+relu / bf16 out ---
template <int K, int NN, bool RELU, bool OBF>
__global__ __launch_bounds__(256) void gemm_k(const float* __restrict__ A,
                                              const float* __restrict__ B,
                                              const float* __restrict__ bias,
                                              float* __restrict__ C, int M) {
    constexpr int BM = 64;
    constexpr int TM = 8;
    constexpr int TN = NN / 32;
    static_assert(!OBF || (TN % 2 == 0), "bf16 pack needs even TN");
    __shared__ float As[BM * K];
    __shared__ float Bs[K * NN];
    const int tid = threadIdx.x;
    const int row0 = blockIdx.x * BM;

    {
        const float4* B4 = (const float4*)B;
        float4* Bs4 = (float4*)Bs;
        for (int i = tid; i < K * NN / 4; i += 256) Bs4[i] = B4[i];
        float4* As4 = (float4*)As;
        for (int i = tid; i < BM * K / 4; i += 256) {
            int idx = i * 4;
            int r = idx / K;
            int gr = row0 + r;
            float4 v = make_float4(0.f, 0.f, 0.f, 0.f);
            if (gr < M) v = *(const float4*)(A + (size_t)gr * K + (idx & (K - 1)));
            As4[i] = v;
        }
    }
    __syncthreads();

    const int rg = tid >> 5;  // 0..7
    const int cg = tid & 31;  // 0..31
    float acc[TM][TN];
#pragma unroll
    for (int i = 0; i < TM; ++i)
#pragma unroll
        for (int j = 0; j < TN; ++j) acc[i][j] = 0.f;

#pragma unroll 4
    for (int k = 0; k < K; ++k) {
        float a[TM], b[TN];
#pragma unroll
        for (int i = 0; i < TM; ++i) a[i] = As[(rg * TM + i) * K + k];
#pragma unroll
        for (int j = 0; j < TN; ++j) b[j] = Bs[k * NN + cg * TN + j];
#pragma unroll
        for (int i = 0; i < TM; ++i)
#pragma unroll
            for (int j = 0; j < TN; ++j) acc[i][j] = fmaf(a[i], b[j], acc[i][j]);
    }

    float bb[TN];
    if (RELU) {
#pragma unroll
        for (int j = 0; j < TN; ++j) bb[j] = bias[cg * TN + j];
    }
#pragma unroll
    for (int i = 0; i < TM; ++i) {
        int r = row0 + rg * TM + i;
        if (r < M) {
            if (OBF) {
                unsigned int* C2 = (unsigned int*)C;
#pragma unroll
                for (int j = 0; j < TN; j += 2) {
                    unsigned int pk = (unsigned int)f2bf(acc[i][j]) |
                                      ((unsigned int)f2bf(acc[i][j + 1]) << 16);
                    C2[((size_t)r * NN + cg * TN + j) >> 1] = pk;
                }
            } else {
#pragma unroll
                for (int j = 0; j < TN; ++j) {
                    float v = acc[i][j];
                    if (RELU) v = fmaxf(v + bb[j], 0.f);
                    C[(size_t)r * NN + cg * TN + j] = v;
                }
            }
        }
    }
}

// ---------------- launch -----------------------------------------------------
extern "C" void kernel_launch(void* const* d_in, const int* in_sizes, int n_in,
                              void* d_out, int out_size, void* d_ws, size_t ws_size,
                              hipStream_t stream) {
    (void)n_in; (void)out_size; (void)ws_size;
    const float* x  = (const float*)d_in[0];
    const void*  ei = d_in[1];
    const float* W1 = (const float*)d_in[2];
    const float* b1 = (const float*)d_in[3];
    const float* W2 = (const float*)d_in[4];
    const float* b2 = (const float*)d_in[5];
    float* out = (float*)d_out;
    const int N = in_sizes[0] / IN_C;   // 50000
    const int E = in_sizes[1] / 2;      // 800000
    const int NB = (N + 255) / 256;     // scan blocks / buckets (196)
    const int PB = (E + CH - 1) / CH;   // partition blocks (196)
    const int NC4 = N * IN_C / 4;       // x float4 count (800000)

    char* p = (char*)d_ws;
    auto take = [&](size_t bytes) {
        char* r = p;
        p += (bytes + 255) & ~(size_t)255;
        return r;
    };
    int*   indeg   = (int*)take((size_t)N * 4);
    int*   flag    = (int*)take(256);
    int*   rowptr  = (int*)take(((size_t)N + 1) * 4);
    float* dinv    = (float*)take((size_t)N * 4);
    int*   bsum    = (int*)take(1024);
    int*   boff    = (int*)take(1024);
    int*   gcursor = (int*)take(1024);
    int2*  edata   = (int2*)take((size_t)E * 8);
    uint2* xbf     = (uint2*)take((size_t)N * IN_C * 2);   // bf16 x table
    uint2* hwb     = (uint2*)take((size_t)N * OUT_C * 2);  // bf16 hW2 table
    float* agg1    = (float*)take((size_t)N * IN_C * 4);
    float* h       = (float*)take((size_t)N * HID_C * 4);
    int2*  tmp     = (int2*)agg1;  // alias: tmp COO dead before agg1 is written

    init_conv_k<<<(NC4 + 255) / 256, 256, 0, stream>>>(
        (const unsigned int*)ei, flag, indeg, (const float4*)x, xbf, N, NC4);
    count_deg<<<(E + 255) / 256, 256, 0, stream>>>(ei, E, flag, indeg);
    partial_scan_k<<<NB, 256, 0, stream>>>(indeg, rowptr, dinv, bsum, N);
    scan_sums_k<<<1, 256, 0, stream>>>(bsum, boff, NB);
    add_off_k<<<NB, 256, 0, stream>>>(rowptr, boff, gcursor, N, E);
    partition_k<<<PB, 256, 0, stream>>>(ei, E, flag, gcursor, tmp);
    bucket_fill_k<<<NB, 256, 0, stream>>>(tmp, rowptr, dinv, edata, N);

    // layer 1: agg1 = A_hat x (bf16 gathers); h = relu(agg1 @ W1 + b1)
    aggregate_bf16_k<false><<<(N + 15) / 16, 256, 0, stream>>>(
        xbf, rowptr, edata, dinv, nullptr, (float4*)agg1, N);
    gemm_k<IN_C, HID_C, true, false><<<(N + 63) / 64, 256, 0, stream>>>(agg1, W1, b1, h, N);

    // layer 2: hwb = bf16(h @ W2) ; out = A_hat hwb + b2
    gemm_k<HID_C, OUT_C, false, true><<<(N + 63) / 64, 256, 0, stream>>>(h, W2, nullptr,
                                                                         (float*)hwb, N);
    aggregate_bf16_k<true><<<(N + 15) / 16, 256, 0, stream>>>(
        hwb, rowptr, edata, dinv, (const float4*)b2, (float4*)out, N);
}